// Round 3
// baseline (272.594 us; speedup 1.0000x reference)
//
#include <hip/hip_runtime.h>
#include <stdint.h>

// B=4, T=2048, C=1024, H=16, D=64, R=32
// Pipeline: cvt -> qkv3_gemm(fused QKV, dbuf) -> attn(8-wave blocks, hoisted
//   K/V frags, h-pipelined P exchange) -> out_gemm(dbuf)

typedef __attribute__((ext_vector_type(8))) short bf16x8;   // 8 bf16 (4 VGPRs)
typedef __attribute__((ext_vector_type(4))) float f32x4;    // MFMA accumulator
typedef __attribute__((ext_vector_type(4))) short short4v;  // 8-byte packed store
typedef __attribute__((ext_vector_type(2))) uint32_t uint2v;

#define MFMA16(a, b, c) __builtin_amdgcn_mfma_f32_16x16x32_bf16((a), (b), (c), 0, 0, 0)

#if __has_builtin(__builtin_amdgcn_exp2f)
#define FEXP(x) __builtin_amdgcn_exp2f(x)
#define QSCALE 0.18033688011112042f  // 0.125 * log2(e)
#else
#define FEXP(x) __expf(x)
#define QSCALE 0.125f
#endif

static __device__ __forceinline__ short f2bf(float f) {
  union { float fv; uint32_t u; } v; v.fv = f;
  uint32_t r = v.u + 0x7FFFu + ((v.u >> 16) & 1u);  // RNE
  return (short)(r >> 16);
}

// pack two fp32 -> two bf16 (truncation) in one v_perm_b32
static __device__ __forceinline__ uint32_t pack_trunc(float a, float b) {
  union { float f; uint32_t u; } ua, ub;
  ua.f = a; ub.f = b;
#if __has_builtin(__builtin_amdgcn_perm)
  return __builtin_amdgcn_perm(ub.u, ua.u, 0x07060302u);
#else
  return (ub.u & 0xFFFF0000u) | (ua.u >> 16);
#endif
}

typedef __attribute__((address_space(1))) void as1_void;
typedef __attribute__((address_space(3))) void as3_void;
static __device__ __forceinline__ void gld_lds16(const void* g, void* l) {
  __builtin_amdgcn_global_load_lds((as1_void*)g, (as3_void*)l, 16, 0, 0);
}

// ---------------------------------------------------------------------------
// Kernel 1: fp32 -> bf16 conversion for x, Wq, Wk, Wv, Wo
// ---------------------------------------------------------------------------
__global__ __launch_bounds__(256) void cvt_kernel(
    const float* x, const float* wq, const float* wk, const float* wv,
    const float* wo,
    short* xb, short* wqb, short* wkb, short* wvb, short* wob) {
  int64_t g = (int64_t)blockIdx.x * 256 + threadIdx.x;  // unit = 4 floats
  const int64_t NX = 8388608 / 4, NW = 1048576 / 4;
  const float* src;
  short* dst;
  int64_t i;
  if (g < NX)               { src = x;  dst = xb;  i = g; }
  else if (g < NX + NW)     { src = wq; dst = wqb; i = g - NX; }
  else if (g < NX + 2 * NW) { src = wk; dst = wkb; i = g - NX - NW; }
  else if (g < NX + 3 * NW) { src = wv; dst = wvb; i = g - NX - 2 * NW; }
  else                      { src = wo; dst = wob; i = g - NX - 3 * NW; }
  float4 v = ((const float4*)src)[i];
  short4v o;
  o[0] = f2bf(v.x); o[1] = f2bf(v.y); o[2] = f2bf(v.z); o[3] = f2bf(v.w);
  *(short4v*)&dst[i * 4] = o;
}

// ---------------------------------------------------------------------------
// Kernel 2: fused QKV projection (M=8192, N=1024 x3, K=1024), BK=32.
//   One A-tile stage feeds 3 B-tiles: 48 MFMA per barrier. Double-buffered
//   staging issued right after the barrier.
//   Q: scaled by QSCALE; K,V: masked rows zeroed.
//   Q,K written [bh][t][64] bf16; V written [bh][64][t] bf16 (transposed).
// ---------------------------------------------------------------------------
__global__ __launch_bounds__(256, 2) void qkv3_gemm(
    const short* __restrict__ Xb,
    const short* __restrict__ Wq, const short* __restrict__ Wk,
    const short* __restrict__ Wv,
    const float* __restrict__ bq, const float* __restrict__ bk,
    const float* __restrict__ bv,
    const float* __restrict__ rope, const int* __restrict__ mask,
    short* __restrict__ Qh, short* __restrict__ Kh, short* __restrict__ Vt) {
  __shared__ __align__(16) short As[2][128 * 32];     // 16 KB
  __shared__ __align__(16) short Bs[2][3][128 * 32];  // 48 KB

  const int t = threadIdx.x;
  const int lane = t & 63;
  const int wave = t >> 6;
  const int c = lane & 15;
  const int quad = lane >> 4;
  const int m0 = blockIdx.x * 128;
  const int n0 = blockIdx.y * 128;

  f32x4 zero4 = {0.f, 0.f, 0.f, 0.f};
  f32x4 acc[3][4][4];
#pragma unroll
  for (int m = 0; m < 3; ++m)
#pragma unroll
    for (int i = 0; i < 4; ++i)
#pragma unroll
      for (int j = 0; j < 4; ++j) acc[m][i][j] = zero4;

  const int wm = wave & 1, wn = wave >> 1;

  const int srow = t >> 2;
  const int gc = ((t & 3) - (srow >> 2)) & 3;
  const short* gA = Xb + (size_t)(m0 + srow) * 1024 + gc * 8;
  const short* gW0 = Wq + (size_t)(n0 + srow) * 1024 + gc * 8;
  const short* gW1 = Wk + (size_t)(n0 + srow) * 1024 + gc * 8;
  const short* gW2 = Wv + (size_t)(n0 + srow) * 1024 + gc * 8;

#define QKV_STAGE(buf, k0)                                  \
  do {                                                      \
    gld_lds16(gA + (k0), &As[buf][t * 8]);                  \
    gld_lds16(gA + (k0) + 65536, &As[buf][t * 8 + 2048]);   \
    gld_lds16(gW0 + (k0), &Bs[buf][0][t * 8]);              \
    gld_lds16(gW0 + (k0) + 65536, &Bs[buf][0][t * 8 + 2048]); \
    gld_lds16(gW1 + (k0), &Bs[buf][1][t * 8]);              \
    gld_lds16(gW1 + (k0) + 65536, &Bs[buf][1][t * 8 + 2048]); \
    gld_lds16(gW2 + (k0), &Bs[buf][2][t * 8]);              \
    gld_lds16(gW2 + (k0) + 65536, &Bs[buf][2][t * 8 + 2048]); \
  } while (0)

  QKV_STAGE(0, 0);

  for (int ki = 0; ki < 32; ++ki) {
    __syncthreads();  // drains buf[ki&1] loads (issued one compute phase ago)
    if (ki < 31) QKV_STAGE((ki + 1) & 1, (ki + 1) * 32);

    const short* as = &As[ki & 1][0];
    bf16x8 af[4];
#pragma unroll
    for (int i = 0; i < 4; ++i) {
      int mr = wm * 64 + i * 16 + c;
      af[i] = *(const bf16x8*)&as[mr * 32 + (((quad + (mr >> 2)) & 3) * 8)];
    }
#pragma unroll
    for (int m = 0; m < 3; ++m) {
      const short* bs = &Bs[ki & 1][m][0];
      bf16x8 bfr[4];
#pragma unroll
      for (int j = 0; j < 4; ++j) {
        int nr = wn * 64 + j * 16 + c;
        bfr[j] = *(const bf16x8*)&bs[nr * 32 + (((quad + (nr >> 2)) & 3) * 8)];
      }
#pragma unroll
      for (int i = 0; i < 4; ++i)
#pragma unroll
        for (int j = 0; j < 4; ++j)
          acc[m][i][j] = MFMA16(af[i], bfr[j], acc[m][i][j]);
    }
  }
#undef QKV_STAGE

  // ---- epilogue: C/D layout col=lane&15, row=quad*4+reg ----
  const int nb = n0 + wn * 64;  // wave's 64 cols == one head
  const int hcol = nb >> 6;
  const int bidx = m0 >> 11;
  const int tbase = (m0 & 2047) + wm * 64 + quad * 4;
  const int* mrow = mask + bidx * 2048;

  // Q (mat 0) and K (mat 1): [bh][t][64] with RoPE
#pragma unroll
  for (int mat = 0; mat < 2; ++mat) {
    short* Og = (mat == 0) ? Qh : Kh;
    const float* bias = (mat == 0) ? bq : bk;
    float bj[4];
#pragma unroll
    for (int j = 0; j < 4; ++j) bj[j] = bias[nb + j * 16 + c];
    size_t hb = (size_t)(bidx * 16 + hcol) * 2048;
#pragma unroll
    for (int i = 0; i < 4; ++i) {
#pragma unroll
      for (int r = 0; r < 4; ++r) {
        int tp = tbase + i * 16 + r;
        float f = (mat == 0) ? QSCALE : (mrow[tp] ? 1.0f : 0.0f);
        float cosv = rope[tp * 32 + c];
        float sinv = rope[65536 + tp * 32 + c];
        float v0 = acc[mat][i][0][r] + bj[0];
        float v1 = acc[mat][i][1][r] + bj[1];
        float v2 = acc[mat][i][2][r] + bj[2];
        float v3 = acc[mat][i][3][r] + bj[3];
        size_t base = (hb + tp) * 64;
        Og[base + c]      = f2bf((v0 * cosv - v1 * sinv) * f);
        Og[base + 16 + c] = f2bf((v1 * cosv + v0 * sinv) * f);
        Og[base + 32 + c] = f2bf(v2 * f);
        Og[base + 48 + c] = f2bf(v3 * f);
      }
    }
  }
  // V (mat 2): transposed [bh][d][t], masked t zeroed
  {
    float bj[4];
#pragma unroll
    for (int j = 0; j < 4; ++j) bj[j] = bv[nb + j * 16 + c];
    size_t hb = (size_t)(bidx * 16 + hcol) * 64;
#pragma unroll
    for (int i = 0; i < 4; ++i) {
      int tp = tbase + i * 16;  // multiple of 4
      int4 mv = *(const int4*)&mrow[tp];
      float fr[4];
      fr[0] = mv.x ? 1.f : 0.f; fr[1] = mv.y ? 1.f : 0.f;
      fr[2] = mv.z ? 1.f : 0.f; fr[3] = mv.w ? 1.f : 0.f;
#pragma unroll
      for (int j = 0; j < 4; ++j) {
        short4v pv;
#pragma unroll
        for (int r = 0; r < 4; ++r)
          pv[r] = f2bf((acc[2][i][j][r] + bj[j]) * fr[r]);
        size_t base = (hb + j * 16 + c) * 2048 + tp;
        *(short4v*)&Vt[base] = pv;
      }
    }
  }
}

// ---------------------------------------------------------------------------
// Kernel 3: attention, static softmax. 256 q-rows/block, EIGHT waves of 32
//   q-rows each (512 threads): same per-block K/V stream + chunk count as the
//   4-wave/256-row version (round-0 amortization), but 4 waves/SIMD instead
//   of 2 -> 2x the independent chunk-pipelines per SIMD to hide the serial
//   chain (ds_read latency, exp, P round-trip, barrier).
//   bh-major grid keeps each head's K/V on one XCD (FETCH ~25MB, round-2).
//   h-pipelined P exchange with counted lgkmcnt(4)/(2).
//   LDS = 16(K) + 16(V) + 32(P, 8 waves x 2 halves x 16x64) = 64 KB;
//   2 blocks/CU (grid-limited at 512 blocks).
//   S^T = K*Q^T -> p = exp2(s) -> P(bf16) -> O^T = V^T*P^T; l via ones-A MFMA.
// ---------------------------------------------------------------------------
__global__ __launch_bounds__(512, 4) void attn_kernel(
    const short* __restrict__ Qh, const short* __restrict__ Kh,
    const short* __restrict__ Vt, const int* __restrict__ mask,
    short* __restrict__ Og) {
  __shared__ __align__(16) short Ks[2][64 * 64];     // 16 KB
  __shared__ __align__(16) short Vs[2][64 * 64];     // 16 KB
  __shared__ __align__(16) short Pl[8][2][16 * 64];  // 32 KB, per-wave per-half

  const int t = threadIdx.x;
  const int lane = t & 63;
  const int wave = t >> 6;  // 0..7
  const int c = lane & 15;
  const int quad = lane >> 4;
  const int bh = blockIdx.x;   // 0..63 (x-major: head -> fixed XCD)
  const int qt = blockIdx.y;   // 0..7 (256 q rows each)
  const int bidx = bh >> 4;
  const short* Qg = Qh + ((size_t)bh * 2048 + qt * 256) * 64;
  const short* Kg = Kh + (size_t)bh * 2048 * 64;
  const short* Vg = Vt + (size_t)bh * 64 * 2048;

  // count masked keys for this batch; full butterfly so every lane holds the
  // total (in-register, no LDS scalar / extra barrier dependence)
  float nm;
  {
    const int4* mr = (const int4*)(mask + bidx * 2048);
    int cnt = 0;
#pragma unroll
    for (int k = 0; k < 8; ++k) {
      int4 a = mr[k * 64 + lane];
      cnt += (a.x == 0) + (a.y == 0) + (a.z == 0) + (a.w == 0);
    }
    cnt += __shfl_xor(cnt, 1);  cnt += __shfl_xor(cnt, 2);
    cnt += __shfl_xor(cnt, 4);  cnt += __shfl_xor(cnt, 8);
    cnt += __shfl_xor(cnt, 16); cnt += __shfl_xor(cnt, 32);
    nm = (float)cnt;
  }

  // Q fragments (B-operand), loop-invariant; wave covers 32 q rows (it 0..1)
  bf16x8 qf[2][2];
#pragma unroll
  for (int ks = 0; ks < 2; ++ks)
#pragma unroll
    for (int it = 0; it < 2; ++it)
      qf[ks][it] =
          *(const bf16x8*)&Qg[(wave * 32 + it * 16 + c) * 64 + ks * 32 + quad * 8];

  const bf16x8 ones = {0x3F80, 0x3F80, 0x3F80, 0x3F80,
                       0x3F80, 0x3F80, 0x3F80, 0x3F80};  // bf16 1.0 x8

  f32x4 zero4 = {0.f, 0.f, 0.f, 0.f};
  f32x4 O[4][2];
#pragma unroll
  for (int dt = 0; dt < 4; ++dt)
#pragma unroll
    for (int it = 0; it < 2; ++it) O[dt][it] = zero4;
  f32x4 Ol[2] = {zero4, zero4};

  // staging: 512 threads x 16B = one full 64x64 bf16 tile per buffer
  const int krow0 = t >> 3;                 // 0..63
  const int klc = (t & 7) ^ (krow0 & 7);    // XOR-swizzled col block
  const short* gk0 = Kg + (size_t)krow0 * 64 + klc * 8;
  const short* gv0 = Vg + (size_t)krow0 * 2048 + klc * 8;

  // prologue: stage chunk 0 into buffer 0
  gld_lds16(gk0, &Ks[0][t * 8]);
  gld_lds16(gv0, &Vs[0][t * 8]);

  for (int ci = 0; ci < 32; ++ci) {
    __syncthreads();  // drains chunk-ci loads (issued one compute-phase ago)
    if (ci < 31) {
      int cn = (ci + 1) * 64;
      int nb = (ci + 1) & 1;
      gld_lds16(gk0 + (size_t)cn * 64, &Ks[nb][t * 8]);
      gld_lds16(gv0 + cn, &Vs[nb][t * 8]);
    }
    const short* ksb = &Ks[ci & 1][0];
    const short* vsb = &Vs[ci & 1][0];

    // hoisted K/V fragments (shared by both q-halves)
    bf16x8 ak[2][4], av[2][4];
#pragma unroll
    for (int ks = 0; ks < 2; ++ks)
#pragma unroll
      for (int jt = 0; jt < 4; ++jt) {
        ak[ks][jt] = *(const bf16x8*)&ksb[(jt * 16 + c) * 64 +
                                          (((4 * ks + quad) ^ (c & 7)) * 8)];
        av[ks][jt] = *(const bf16x8*)&vsb[(jt * 16 + c) * 64 +
                                          (((4 * ks + quad) ^ (c & 7)) * 8)];
      }

    // ---- phase A: S-MFMA + exp + P-write for BOTH halves ----
    // h=1's compute hides h=0's P-write latency.
#pragma unroll
    for (int h = 0; h < 2; ++h) {
      f32x4 St[4];
#pragma unroll
      for (int jt = 0; jt < 4; ++jt)
        St[jt] = MFMA16(ak[0][jt], qf[0][h], zero4);
#pragma unroll
      for (int jt = 0; jt < 4; ++jt)
        St[jt] = MFMA16(ak[1][jt], qf[1][h], St[jt]);

      short* Ph = &Pl[wave][h][0];
#pragma unroll
      for (int jt = 0; jt < 4; ++jt) {
        float p0 = FEXP(St[jt][0]);
        float p1 = FEXP(St[jt][1]);
        float p2 = FEXP(St[jt][2]);
        float p3 = FEXP(St[jt][3]);
        uint2v pk;
        pk[0] = pack_trunc(p0, p1);
        pk[1] = pack_trunc(p2, p3);
        *(uint2v*)&Ph[c * 64 +
                      (((jt * 2 + (quad >> 1)) ^ (c & 7)) * 8) +
                      (quad & 1) * 4] = pk;
      }
      // pin P(h) stores before P(h+1) stores (ordering needed for the
      // counted lgkmcnt below); register-only ops still interleave freely.
      asm volatile("" ::: "memory");
    }

    // P0's 4 writes retired when <=4 outstanding (the 4 P1 writes always
    // follow the last P0 write in issue order; LDS retires in-order).
    asm volatile("s_waitcnt lgkmcnt(4)" ::: "memory");

    // ---- phase B: P-read + PV-MFMA, h=0 then h=1 ----
#pragma unroll
    for (int h = 0; h < 2; ++h) {
      const short* Ph = &Pl[wave][h][0];
#pragma unroll
      for (int ks = 0; ks < 2; ++ks) {
        bf16x8 bp =
            *(const bf16x8*)&Ph[c * 64 + (((ks * 4 + quad) ^ (c & 7)) * 8)];
        Ol[h] = MFMA16(ones, bp, Ol[h]);
#pragma unroll
        for (int dt = 0; dt < 4; ++dt)
          O[dt][h] = MFMA16(av[ks][dt], bp, O[dt][h]);
      }
      // P1's writes retired when <=2 outstanding (h0's 2 b128 reads follow
      // the last P1 write); PV(h0) MFMAs covered the latency.
      if (h == 0) asm volatile("s_waitcnt lgkmcnt(2)" ::: "memory");
    }
  }

#pragma unroll
  for (int it = 0; it < 2; ++it) {
    float inv = 1.0f / (Ol[it][0] - nm);  // remove masked keys' exp2(0)=1
    int tq = qt * 256 + wave * 32 + it * 16 + c;
    size_t rb = ((size_t)bidx * 2048 + tq) * 1024 + (size_t)(bh & 15) * 64;
#pragma unroll
    for (int dt = 0; dt < 4; ++dt) {
      short4v ov;
#pragma unroll
      for (int r = 0; r < 4; ++r) ov[r] = f2bf(O[dt][it][r] * inv);
      *(short4v*)&Og[rb + dt * 16 + quad * 4] = ov;
    }
  }
}

// ---------------------------------------------------------------------------
// Kernel 4: output projection GEMM: out = attout @ Wo^T + bo (fp32 out).
//   64x128 tile, BK=32, double-buffered staging -> 1024 blocks, 24 KB LDS.
// ---------------------------------------------------------------------------
__global__ __launch_bounds__(256) void out_gemm(
    const short* __restrict__ Ab, const short* __restrict__ Wob,
    const float* __restrict__ bo, float* __restrict__ out) {
  __shared__ __align__(16) short As[2][64 * 32];   // 8 KB
  __shared__ __align__(16) short Bs[2][128 * 32];  // 16 KB

  const int t = threadIdx.x;
  const int lane = t & 63;
  const int wave = t >> 6;
  const int c = lane & 15;
  const int quad = lane >> 4;
  const int m0 = blockIdx.x * 64;
  const int n0 = blockIdx.y * 128;

  f32x4 zero4 = {0.f, 0.f, 0.f, 0.f};
  f32x4 acc[4][2];
#pragma unroll
  for (int i = 0; i < 4; ++i) {
    acc[i][0] = zero4;
    acc[i][1] = zero4;
  }

  const int srow = t >> 2;
  const int gc = ((t & 3) - (srow >> 2)) & 3;
  const short* gA = Ab + (size_t)(m0 + srow) * 1024 + gc * 8;
  const short* gB = Wob + (size_t)(n0 + srow) * 1024 + gc * 8;

#define OUT_STAGE(buf, k0)                                   \
  do {                                                       \
    gld_lds16(gA + (k0), &As[buf][t * 8]);                   \
    gld_lds16(gB + (k0), &Bs[buf][t * 8]);                   \
    gld_lds16(gB + (k0) + 65536, &Bs[buf][t * 8 + 2048]);    \
  } while (0)

  OUT_STAGE(0, 0);

  for (int ki = 0; ki < 32; ++ki) {
    __syncthreads();
    if (ki < 31) OUT_STAGE((ki + 1) & 1, (ki + 1) * 32);

    const short* as = &As[ki & 1][0];
    const short* bs = &Bs[ki & 1][0];
    bf16x8 af[4], bfr[2];
#pragma unroll
    for (int i = 0; i < 4; ++i) {
      int mr = i * 16 + c;
      af[i] = *(const bf16x8*)&as[mr * 32 + (((quad + (mr >> 2)) & 3) * 8)];
    }
#pragma unroll
    for (int j = 0; j < 2; ++j) {
      int nr = wave * 32 + j * 16 + c;
      bfr[j] = *(const bf16x8*)&bs[nr * 32 + (((quad + (nr >> 2)) & 3) * 8)];
    }
#pragma unroll
    for (int i = 0; i < 4; ++i) {
      acc[i][0] = MFMA16(af[i], bfr[0], acc[i][0]);
      acc[i][1] = MFMA16(af[i], bfr[1], acc[i][1]);
    }
  }
#undef OUT_STAGE

  const int nb = n0 + wave * 32;
  float bj[2];
  bj[0] = bo[nb + c];
  bj[1] = bo[nb + 16 + c];
#pragma unroll
  for (int i = 0; i < 4; ++i) {
    int m = m0 + i * 16 + quad * 4;
#pragma unroll
    for (int r = 0; r < 4; ++r) {
      float* orow = out + (size_t)(m + r) * 1024 + nb;
      orow[c]      = acc[i][0][r] + bj[0];
      orow[16 + c] = acc[i][1][r] + bj[1];
    }
  }
}

// ---------------------------------------------------------------------------
extern "C" void kernel_launch(void* const* d_in, const int* in_sizes, int n_in,
                              void* d_out, int out_size, void* d_ws,
                              size_t ws_size, hipStream_t stream) {
  const float* x    = (const float*)d_in[0];
  const float* rope = (const float*)d_in[1];
  const int*   mask = (const int*)d_in[2];
  const float* Wq   = (const float*)d_in[3];
  const float* bq   = (const float*)d_in[4];
  const float* Wk   = (const float*)d_in[5];
  const float* bk   = (const float*)d_in[6];
  const float* Wv   = (const float*)d_in[7];
  const float* bv   = (const float*)d_in[8];
  const float* Wo   = (const float*)d_in[9];
  const float* bo   = (const float*)d_in[10];
  float* out = (float*)d_out;

  char* ws = (char*)d_ws;
  short* xb  = (short*)(ws);               // 16 MB; reused as attout later
  short* wqb = (short*)(ws + 16777216);    // 2 MB each
  short* wkb = (short*)(ws + 18874368);
  short* wvb = (short*)(ws + 20971520);
  short* wob = (short*)(ws + 23068672);
  short* Qh  = (short*)(ws + 25198592);    // 16 MB  [bh][t][64]
  short* Kh  = (short*)(ws + 41975808);    // 16 MB  [bh][t][64]
  short* Vt  = (short*)(ws + 58753024);    // 16 MB  [bh][64][t]
  short* att = xb;  // safe: xb consumed by qkv3_gemm before attn writes

  cvt_kernel<<<12288, 256, 0, stream>>>(x, Wq, Wk, Wv, Wo, xb, wqb, wkb, wvb,
                                        wob);
  qkv3_gemm<<<dim3(64, 8), 256, 0, stream>>>(xb, wqb, wkb, wvb, bq, bk, bv,
                                             rope, mask, Qh, Kh, Vt);
  attn_kernel<<<dim3(64, 8), 512, 0, stream>>>(Qh, Kh, Vt, mask, att);
  out_gemm<<<dim3(128, 8), 256, 0, stream>>>(att, wob, bo, out);
}

// Round 4
// 264.514 us; speedup vs baseline: 1.0305x; 1.0305x over previous
//
#include <hip/hip_runtime.h>
#include <stdint.h>

// B=4, T=2048, C=1024, H=16, D=64, R=32
// Pipeline: cvt -> qkv3_gemm(fused QKV, dbuf) -> attn(8-wave blocks, 3-buffer
//   counted-vmcnt K/V pipeline, hoisted K/V frags, h-pipelined P exchange)
//   -> out_gemm(dbuf)

typedef __attribute__((ext_vector_type(8))) short bf16x8;   // 8 bf16 (4 VGPRs)
typedef __attribute__((ext_vector_type(4))) float f32x4;    // MFMA accumulator
typedef __attribute__((ext_vector_type(4))) short short4v;  // 8-byte packed store
typedef __attribute__((ext_vector_type(2))) uint32_t uint2v;

#define MFMA16(a, b, c) __builtin_amdgcn_mfma_f32_16x16x32_bf16((a), (b), (c), 0, 0, 0)

#if __has_builtin(__builtin_amdgcn_exp2f)
#define FEXP(x) __builtin_amdgcn_exp2f(x)
#define QSCALE 0.18033688011112042f  // 0.125 * log2(e)
#else
#define FEXP(x) __expf(x)
#define QSCALE 0.125f
#endif

static __device__ __forceinline__ short f2bf(float f) {
  union { float fv; uint32_t u; } v; v.fv = f;
  uint32_t r = v.u + 0x7FFFu + ((v.u >> 16) & 1u);  // RNE
  return (short)(r >> 16);
}

// pack two fp32 -> two bf16 (truncation) in one v_perm_b32
static __device__ __forceinline__ uint32_t pack_trunc(float a, float b) {
  union { float f; uint32_t u; } ua, ub;
  ua.f = a; ub.f = b;
#if __has_builtin(__builtin_amdgcn_perm)
  return __builtin_amdgcn_perm(ub.u, ua.u, 0x07060302u);
#else
  return (ub.u & 0xFFFF0000u) | (ua.u >> 16);
#endif
}

typedef __attribute__((address_space(1))) void as1_void;
typedef __attribute__((address_space(3))) void as3_void;
static __device__ __forceinline__ void gld_lds16(const void* g, void* l) {
  __builtin_amdgcn_global_load_lds((as1_void*)g, (as3_void*)l, 16, 0, 0);
}

// ---------------------------------------------------------------------------
// Kernel 1: fp32 -> bf16 conversion for x, Wq, Wk, Wv, Wo
// ---------------------------------------------------------------------------
__global__ __launch_bounds__(256) void cvt_kernel(
    const float* x, const float* wq, const float* wk, const float* wv,
    const float* wo,
    short* xb, short* wqb, short* wkb, short* wvb, short* wob) {
  int64_t g = (int64_t)blockIdx.x * 256 + threadIdx.x;  // unit = 4 floats
  const int64_t NX = 8388608 / 4, NW = 1048576 / 4;
  const float* src;
  short* dst;
  int64_t i;
  if (g < NX)               { src = x;  dst = xb;  i = g; }
  else if (g < NX + NW)     { src = wq; dst = wqb; i = g - NX; }
  else if (g < NX + 2 * NW) { src = wk; dst = wkb; i = g - NX - NW; }
  else if (g < NX + 3 * NW) { src = wv; dst = wvb; i = g - NX - 2 * NW; }
  else                      { src = wo; dst = wob; i = g - NX - 3 * NW; }
  float4 v = ((const float4*)src)[i];
  short4v o;
  o[0] = f2bf(v.x); o[1] = f2bf(v.y); o[2] = f2bf(v.z); o[3] = f2bf(v.w);
  *(short4v*)&dst[i * 4] = o;
}

// ---------------------------------------------------------------------------
// Kernel 2: fused QKV projection (M=8192, N=1024 x3, K=1024), BK=32.
//   One A-tile stage feeds 3 B-tiles: 48 MFMA per barrier. Double-buffered
//   staging issued right after the barrier.
//   Q: scaled by QSCALE; K,V: masked rows zeroed.
//   Q,K written [bh][t][64] bf16; V written [bh][64][t] bf16 (transposed).
// ---------------------------------------------------------------------------
__global__ __launch_bounds__(256, 2) void qkv3_gemm(
    const short* __restrict__ Xb,
    const short* __restrict__ Wq, const short* __restrict__ Wk,
    const short* __restrict__ Wv,
    const float* __restrict__ bq, const float* __restrict__ bk,
    const float* __restrict__ bv,
    const float* __restrict__ rope, const int* __restrict__ mask,
    short* __restrict__ Qh, short* __restrict__ Kh, short* __restrict__ Vt) {
  __shared__ __align__(16) short As[2][128 * 32];     // 16 KB
  __shared__ __align__(16) short Bs[2][3][128 * 32];  // 48 KB

  const int t = threadIdx.x;
  const int lane = t & 63;
  const int wave = t >> 6;
  const int c = lane & 15;
  const int quad = lane >> 4;
  const int m0 = blockIdx.x * 128;
  const int n0 = blockIdx.y * 128;

  f32x4 zero4 = {0.f, 0.f, 0.f, 0.f};
  f32x4 acc[3][4][4];
#pragma unroll
  for (int m = 0; m < 3; ++m)
#pragma unroll
    for (int i = 0; i < 4; ++i)
#pragma unroll
      for (int j = 0; j < 4; ++j) acc[m][i][j] = zero4;

  const int wm = wave & 1, wn = wave >> 1;

  const int srow = t >> 2;
  const int gc = ((t & 3) - (srow >> 2)) & 3;
  const short* gA = Xb + (size_t)(m0 + srow) * 1024 + gc * 8;
  const short* gW0 = Wq + (size_t)(n0 + srow) * 1024 + gc * 8;
  const short* gW1 = Wk + (size_t)(n0 + srow) * 1024 + gc * 8;
  const short* gW2 = Wv + (size_t)(n0 + srow) * 1024 + gc * 8;

#define QKV_STAGE(buf, k0)                                  \
  do {                                                      \
    gld_lds16(gA + (k0), &As[buf][t * 8]);                  \
    gld_lds16(gA + (k0) + 65536, &As[buf][t * 8 + 2048]);   \
    gld_lds16(gW0 + (k0), &Bs[buf][0][t * 8]);              \
    gld_lds16(gW0 + (k0) + 65536, &Bs[buf][0][t * 8 + 2048]); \
    gld_lds16(gW1 + (k0), &Bs[buf][1][t * 8]);              \
    gld_lds16(gW1 + (k0) + 65536, &Bs[buf][1][t * 8 + 2048]); \
    gld_lds16(gW2 + (k0), &Bs[buf][2][t * 8]);              \
    gld_lds16(gW2 + (k0) + 65536, &Bs[buf][2][t * 8 + 2048]); \
  } while (0)

  QKV_STAGE(0, 0);

  for (int ki = 0; ki < 32; ++ki) {
    __syncthreads();  // drains buf[ki&1] loads (issued one compute phase ago)
    if (ki < 31) QKV_STAGE((ki + 1) & 1, (ki + 1) * 32);

    const short* as = &As[ki & 1][0];
    bf16x8 af[4];
#pragma unroll
    for (int i = 0; i < 4; ++i) {
      int mr = wm * 64 + i * 16 + c;
      af[i] = *(const bf16x8*)&as[mr * 32 + (((quad + (mr >> 2)) & 3) * 8)];
    }
#pragma unroll
    for (int m = 0; m < 3; ++m) {
      const short* bs = &Bs[ki & 1][m][0];
      bf16x8 bfr[4];
#pragma unroll
      for (int j = 0; j < 4; ++j) {
        int nr = wn * 64 + j * 16 + c;
        bfr[j] = *(const bf16x8*)&bs[nr * 32 + (((quad + (nr >> 2)) & 3) * 8)];
      }
#pragma unroll
      for (int i = 0; i < 4; ++i)
#pragma unroll
        for (int j = 0; j < 4; ++j)
          acc[m][i][j] = MFMA16(af[i], bfr[j], acc[m][i][j]);
    }
  }
#undef QKV_STAGE

  // ---- epilogue: C/D layout col=lane&15, row=quad*4+reg ----
  const int nb = n0 + wn * 64;  // wave's 64 cols == one head
  const int hcol = nb >> 6;
  const int bidx = m0 >> 11;
  const int tbase = (m0 & 2047) + wm * 64 + quad * 4;
  const int* mrow = mask + bidx * 2048;

  // Q (mat 0) and K (mat 1): [bh][t][64] with RoPE
#pragma unroll
  for (int mat = 0; mat < 2; ++mat) {
    short* Og = (mat == 0) ? Qh : Kh;
    const float* bias = (mat == 0) ? bq : bk;
    float bj[4];
#pragma unroll
    for (int j = 0; j < 4; ++j) bj[j] = bias[nb + j * 16 + c];
    size_t hb = (size_t)(bidx * 16 + hcol) * 2048;
#pragma unroll
    for (int i = 0; i < 4; ++i) {
#pragma unroll
      for (int r = 0; r < 4; ++r) {
        int tp = tbase + i * 16 + r;
        float f = (mat == 0) ? QSCALE : (mrow[tp] ? 1.0f : 0.0f);
        float cosv = rope[tp * 32 + c];
        float sinv = rope[65536 + tp * 32 + c];
        float v0 = acc[mat][i][0][r] + bj[0];
        float v1 = acc[mat][i][1][r] + bj[1];
        float v2 = acc[mat][i][2][r] + bj[2];
        float v3 = acc[mat][i][3][r] + bj[3];
        size_t base = (hb + tp) * 64;
        Og[base + c]      = f2bf((v0 * cosv - v1 * sinv) * f);
        Og[base + 16 + c] = f2bf((v1 * cosv + v0 * sinv) * f);
        Og[base + 32 + c] = f2bf(v2 * f);
        Og[base + 48 + c] = f2bf(v3 * f);
      }
    }
  }
  // V (mat 2): transposed [bh][d][t], masked t zeroed
  {
    float bj[4];
#pragma unroll
    for (int j = 0; j < 4; ++j) bj[j] = bv[nb + j * 16 + c];
    size_t hb = (size_t)(bidx * 16 + hcol) * 64;
#pragma unroll
    for (int i = 0; i < 4; ++i) {
      int tp = tbase + i * 16;  // multiple of 4
      int4 mv = *(const int4*)&mrow[tp];
      float fr[4];
      fr[0] = mv.x ? 1.f : 0.f; fr[1] = mv.y ? 1.f : 0.f;
      fr[2] = mv.z ? 1.f : 0.f; fr[3] = mv.w ? 1.f : 0.f;
#pragma unroll
      for (int j = 0; j < 4; ++j) {
        short4v pv;
#pragma unroll
        for (int r = 0; r < 4; ++r)
          pv[r] = f2bf((acc[2][i][j][r] + bj[j]) * fr[r]);
        size_t base = (hb + j * 16 + c) * 2048 + tp;
        *(short4v*)&Vt[base] = pv;
      }
    }
  }
}

// ---------------------------------------------------------------------------
// Kernel 3: attention, static softmax. 256 q-rows/block, 8 waves x 32 q-rows
//   (512 threads). Round-4 change: 3-buffer K/V staging with counted-vmcnt
//   pipeline (depth 2) + raw s_barrier instead of __syncthreads — removes the
//   per-chunk vmcnt(0) drain that serialized staging latency with compute
//   (T3/T4). Each wave issues exactly 2 gld_lds per chunk, so vmcnt(2) at
//   chunk top certifies this chunk's loads landed while next chunk's stay in
//   flight across the barrier; chunk ci stages ci+2 right after the barrier.
//   Buffer reuse (ci+2 == ci-1 mod 3) is barrier-protected; sched_barrier(0)
//   pins ds_reads below the s_barrier (rule 18/21).
//   bh-major grid keeps each head's K/V on one XCD (FETCH ~26MB).
//   h-pipelined P exchange with counted lgkmcnt(4)/(2).
//   LDS = 24(K) + 24(V) + 32(P) = 80 KB; 2 blocks/CU = 160 KB (exact cap).
//   S^T = K*Q^T -> p = exp2(s) -> P(bf16) -> O^T = V^T*P^T; l via ones-A MFMA.
// ---------------------------------------------------------------------------
__global__ __launch_bounds__(512, 4) void attn_kernel(
    const short* __restrict__ Qh, const short* __restrict__ Kh,
    const short* __restrict__ Vt, const int* __restrict__ mask,
    short* __restrict__ Og) {
  __shared__ __align__(16) short Ks[3][64 * 64];     // 24 KB
  __shared__ __align__(16) short Vs[3][64 * 64];     // 24 KB
  __shared__ __align__(16) short Pl[8][2][16 * 64];  // 32 KB, per-wave per-half

  const int t = threadIdx.x;
  const int lane = t & 63;
  const int wave = t >> 6;  // 0..7
  const int c = lane & 15;
  const int quad = lane >> 4;
  const int bh = blockIdx.x;   // 0..63 (x-major: head -> fixed XCD)
  const int qt = blockIdx.y;   // 0..7 (256 q rows each)
  const int bidx = bh >> 4;
  const short* Qg = Qh + ((size_t)bh * 2048 + qt * 256) * 64;
  const short* Kg = Kh + (size_t)bh * 2048 * 64;
  const short* Vg = Vt + (size_t)bh * 64 * 2048;

  // staging addresses: 512 threads x 16B = one full 64x64 bf16 tile per buffer
  const int krow0 = t >> 3;                 // 0..63
  const int klc = (t & 7) ^ (krow0 & 7);    // XOR-swizzled col block
  const short* gk0 = Kg + (size_t)krow0 * 64 + klc * 8;
  const short* gv0 = Vg + (size_t)krow0 * 2048 + klc * 8;

  // prologue: stage chunks 0 and 1 (4 outstanding gld_lds per wave)
  gld_lds16(gk0, &Ks[0][t * 8]);
  gld_lds16(gv0, &Vs[0][t * 8]);
  gld_lds16(gk0 + (size_t)64 * 64, &Ks[1][t * 8]);
  gld_lds16(gv0 + 64, &Vs[1][t * 8]);

  // count masked keys for this batch; full butterfly so every lane holds the
  // total (in-register, no LDS scalar / extra barrier dependence)
  float nm;
  {
    const int4* mr = (const int4*)(mask + bidx * 2048);
    int cnt = 0;
#pragma unroll
    for (int k = 0; k < 8; ++k) {
      int4 a = mr[k * 64 + lane];
      cnt += (a.x == 0) + (a.y == 0) + (a.z == 0) + (a.w == 0);
    }
    cnt += __shfl_xor(cnt, 1);  cnt += __shfl_xor(cnt, 2);
    cnt += __shfl_xor(cnt, 4);  cnt += __shfl_xor(cnt, 8);
    cnt += __shfl_xor(cnt, 16); cnt += __shfl_xor(cnt, 32);
    nm = (float)cnt;
  }

  // Q fragments (B-operand), loop-invariant; wave covers 32 q rows (it 0..1)
  bf16x8 qf[2][2];
#pragma unroll
  for (int ks = 0; ks < 2; ++ks)
#pragma unroll
    for (int it = 0; it < 2; ++it)
      qf[ks][it] =
          *(const bf16x8*)&Qg[(wave * 32 + it * 16 + c) * 64 + ks * 32 + quad * 8];

  const bf16x8 ones = {0x3F80, 0x3F80, 0x3F80, 0x3F80,
                       0x3F80, 0x3F80, 0x3F80, 0x3F80};  // bf16 1.0 x8

  f32x4 zero4 = {0.f, 0.f, 0.f, 0.f};
  f32x4 O[4][2];
#pragma unroll
  for (int dt = 0; dt < 4; ++dt)
#pragma unroll
    for (int it = 0; it < 2; ++it) O[dt][it] = zero4;
  f32x4 Ol[2] = {zero4, zero4};

  int bcur = 0;  // buffer holding chunk ci
  for (int ci = 0; ci < 32; ++ci) {
    // certify THIS chunk's 2 loads landed (2 newer ones — next chunk's —
    // stay in flight across the barrier). vmcnt counts in issue order.
    if (ci < 31) {
      asm volatile("s_waitcnt vmcnt(2)" ::: "memory");
    } else {
      asm volatile("s_waitcnt vmcnt(0)" ::: "memory");
    }
    __builtin_amdgcn_s_barrier();       // publish: all waves' slices landed
    __builtin_amdgcn_sched_barrier(0);  // pin ds_reads below the barrier

    if (ci < 30) {
      int cn = (ci + 2) * 64;
      int bst = bcur + 2; if (bst >= 3) bst -= 3;
      gld_lds16(gk0 + (size_t)cn * 64, &Ks[bst][t * 8]);
      gld_lds16(gv0 + cn, &Vs[bst][t * 8]);
    }
    const short* ksb = &Ks[bcur][0];
    const short* vsb = &Vs[bcur][0];

    // hoisted K/V fragments (shared by both q-halves)
    bf16x8 ak[2][4], av[2][4];
#pragma unroll
    for (int ks = 0; ks < 2; ++ks)
#pragma unroll
      for (int jt = 0; jt < 4; ++jt) {
        ak[ks][jt] = *(const bf16x8*)&ksb[(jt * 16 + c) * 64 +
                                          (((4 * ks + quad) ^ (c & 7)) * 8)];
        av[ks][jt] = *(const bf16x8*)&vsb[(jt * 16 + c) * 64 +
                                          (((4 * ks + quad) ^ (c & 7)) * 8)];
      }

    // ---- phase A: S-MFMA + exp + P-write for BOTH halves ----
    // h=1's compute hides h=0's P-write latency.
#pragma unroll
    for (int h = 0; h < 2; ++h) {
      f32x4 St[4];
#pragma unroll
      for (int jt = 0; jt < 4; ++jt)
        St[jt] = MFMA16(ak[0][jt], qf[0][h], zero4);
#pragma unroll
      for (int jt = 0; jt < 4; ++jt)
        St[jt] = MFMA16(ak[1][jt], qf[1][h], St[jt]);

      short* Ph = &Pl[wave][h][0];
#pragma unroll
      for (int jt = 0; jt < 4; ++jt) {
        float p0 = FEXP(St[jt][0]);
        float p1 = FEXP(St[jt][1]);
        float p2 = FEXP(St[jt][2]);
        float p3 = FEXP(St[jt][3]);
        uint2v pk;
        pk[0] = pack_trunc(p0, p1);
        pk[1] = pack_trunc(p2, p3);
        *(uint2v*)&Ph[c * 64 +
                      (((jt * 2 + (quad >> 1)) ^ (c & 7)) * 8) +
                      (quad & 1) * 4] = pk;
      }
      // pin P(h) stores before P(h+1) stores (ordering needed for the
      // counted lgkmcnt below); register-only ops still interleave freely.
      asm volatile("" ::: "memory");
    }

    // P0's 4 writes retired when <=4 outstanding (the 4 P1 writes always
    // follow the last P0 write in issue order; LDS retires in-order).
    asm volatile("s_waitcnt lgkmcnt(4)" ::: "memory");

    // ---- phase B: P-read + PV-MFMA, h=0 then h=1 ----
#pragma unroll
    for (int h = 0; h < 2; ++h) {
      const short* Ph = &Pl[wave][h][0];
#pragma unroll
      for (int ks = 0; ks < 2; ++ks) {
        bf16x8 bp =
            *(const bf16x8*)&Ph[c * 64 + (((ks * 4 + quad) ^ (c & 7)) * 8)];
        Ol[h] = MFMA16(ones, bp, Ol[h]);
#pragma unroll
        for (int dt = 0; dt < 4; ++dt)
          O[dt][h] = MFMA16(av[ks][dt], bp, O[dt][h]);
      }
      // P1's writes retired when <=2 outstanding (h0's 2 b128 reads follow
      // the last P1 write); PV(h0) MFMAs covered the latency.
      if (h == 0) asm volatile("s_waitcnt lgkmcnt(2)" ::: "memory");
    }

    bcur = (bcur + 1 == 3) ? 0 : bcur + 1;
  }

#pragma unroll
  for (int it = 0; it < 2; ++it) {
    float inv = 1.0f / (Ol[it][0] - nm);  // remove masked keys' exp2(0)=1
    int tq = qt * 256 + wave * 32 + it * 16 + c;
    size_t rb = ((size_t)bidx * 2048 + tq) * 1024 + (size_t)(bh & 15) * 64;
#pragma unroll
    for (int dt = 0; dt < 4; ++dt) {
      short4v ov;
#pragma unroll
      for (int r = 0; r < 4; ++r) ov[r] = f2bf(O[dt][it][r] * inv);
      *(short4v*)&Og[rb + dt * 16 + quad * 4] = ov;
    }
  }
}

// ---------------------------------------------------------------------------
// Kernel 4: output projection GEMM: out = attout @ Wo^T + bo (fp32 out).
//   64x128 tile, BK=32, double-buffered staging -> 1024 blocks, 24 KB LDS.
// ---------------------------------------------------------------------------
__global__ __launch_bounds__(256) void out_gemm(
    const short* __restrict__ Ab, const short* __restrict__ Wob,
    const float* __restrict__ bo, float* __restrict__ out) {
  __shared__ __align__(16) short As[2][64 * 32];   // 8 KB
  __shared__ __align__(16) short Bs[2][128 * 32];  // 16 KB

  const int t = threadIdx.x;
  const int lane = t & 63;
  const int wave = t >> 6;
  const int c = lane & 15;
  const int quad = lane >> 4;
  const int m0 = blockIdx.x * 64;
  const int n0 = blockIdx.y * 128;

  f32x4 zero4 = {0.f, 0.f, 0.f, 0.f};
  f32x4 acc[4][2];
#pragma unroll
  for (int i = 0; i < 4; ++i) {
    acc[i][0] = zero4;
    acc[i][1] = zero4;
  }

  const int srow = t >> 2;
  const int gc = ((t & 3) - (srow >> 2)) & 3;
  const short* gA = Ab + (size_t)(m0 + srow) * 1024 + gc * 8;
  const short* gB = Wob + (size_t)(n0 + srow) * 1024 + gc * 8;

#define OUT_STAGE(buf, k0)                                   \
  do {                                                       \
    gld_lds16(gA + (k0), &As[buf][t * 8]);                   \
    gld_lds16(gB + (k0), &Bs[buf][t * 8]);                   \
    gld_lds16(gB + (k0) + 65536, &Bs[buf][t * 8 + 2048]);    \
  } while (0)

  OUT_STAGE(0, 0);

  for (int ki = 0; ki < 32; ++ki) {
    __syncthreads();
    if (ki < 31) OUT_STAGE((ki + 1) & 1, (ki + 1) * 32);

    const short* as = &As[ki & 1][0];
    const short* bs = &Bs[ki & 1][0];
    bf16x8 af[4], bfr[2];
#pragma unroll
    for (int i = 0; i < 4; ++i) {
      int mr = i * 16 + c;
      af[i] = *(const bf16x8*)&as[mr * 32 + (((quad + (mr >> 2)) & 3) * 8)];
    }
#pragma unroll
    for (int j = 0; j < 2; ++j) {
      int nr = wave * 32 + j * 16 + c;
      bfr[j] = *(const bf16x8*)&bs[nr * 32 + (((quad + (nr >> 2)) & 3) * 8)];
    }
#pragma unroll
    for (int i = 0; i < 4; ++i) {
      acc[i][0] = MFMA16(af[i], bfr[0], acc[i][0]);
      acc[i][1] = MFMA16(af[i], bfr[1], acc[i][1]);
    }
  }
#undef OUT_STAGE

  const int nb = n0 + wave * 32;
  float bj[2];
  bj[0] = bo[nb + c];
  bj[1] = bo[nb + 16 + c];
#pragma unroll
  for (int i = 0; i < 4; ++i) {
    int m = m0 + i * 16 + quad * 4;
#pragma unroll
    for (int r = 0; r < 4; ++r) {
      float* orow = out + (size_t)(m + r) * 1024 + nb;
      orow[c]      = acc[i][0][r] + bj[0];
      orow[16 + c] = acc[i][1][r] + bj[1];
    }
  }
}

// ---------------------------------------------------------------------------
extern "C" void kernel_launch(void* const* d_in, const int* in_sizes, int n_in,
                              void* d_out, int out_size, void* d_ws,
                              size_t ws_size, hipStream_t stream) {
  const float* x    = (const float*)d_in[0];
  const float* rope = (const float*)d_in[1];
  const int*   mask = (const int*)d_in[2];
  const float* Wq   = (const float*)d_in[3];
  const float* bq   = (const float*)d_in[4];
  const float* Wk   = (const float*)d_in[5];
  const float* bk   = (const float*)d_in[6];
  const float* Wv   = (const float*)d_in[7];
  const float* bv   = (const float*)d_in[8];
  const float* Wo   = (const float*)d_in[9];
  const float* bo   = (const float*)d_in[10];
  float* out = (float*)d_out;

  char* ws = (char*)d_ws;
  short* xb  = (short*)(ws);               // 16 MB; reused as attout later
  short* wqb = (short*)(ws + 16777216);    // 2 MB each
  short* wkb = (short*)(ws + 18874368);
  short* wvb = (short*)(ws + 20971520);
  short* wob = (short*)(ws + 23068672);
  short* Qh  = (short*)(ws + 25198592);    // 16 MB  [bh][t][64]
  short* Kh  = (short*)(ws + 41975808);    // 16 MB  [bh][t][64]
  short* Vt  = (short*)(ws + 58753024);    // 16 MB  [bh][64][t]
  short* att = xb;  // safe: xb consumed by qkv3_gemm before attn writes

  cvt_kernel<<<12288, 256, 0, stream>>>(x, Wq, Wk, Wv, Wo, xb, wqb, wkb, wvb,
                                        wob);
  qkv3_gemm<<<dim3(64, 8), 256, 0, stream>>>(xb, wqb, wkb, wvb, bq, bk, bv,
                                             rope, mask, Qh, Kh, Vt);
  attn_kernel<<<dim3(64, 8), 512, 0, stream>>>(Qh, Kh, Vt, mask, att);
  out_gemm<<<dim3(128, 8), 256, 0, stream>>>(att, wob, bo, out);
}

// Round 5
// 264.237 us; speedup vs baseline: 1.0316x; 1.0011x over previous
//
#include <hip/hip_runtime.h>
#include <stdint.h>

// B=4, T=2048, C=1024, H=16, D=64, R=32
// Pipeline: cvt -> qkv3_gemm(fused QKV, dbuf) -> attn(in-register P: no P-LDS
//   round trip, k-slot permutation absorbed into V fragment) -> out_gemm(dbuf)

typedef __attribute__((ext_vector_type(8))) short bf16x8;   // 8 bf16 (4 VGPRs)
typedef __attribute__((ext_vector_type(4))) float f32x4;    // MFMA accumulator
typedef __attribute__((ext_vector_type(4))) short short4v;  // 8-byte packed load/store

#define MFMA16(a, b, c) __builtin_amdgcn_mfma_f32_16x16x32_bf16((a), (b), (c), 0, 0, 0)

#if __has_builtin(__builtin_amdgcn_exp2f)
#define FEXP(x) __builtin_amdgcn_exp2f(x)
#define QSCALE 0.18033688011112042f  // 0.125 * log2(e)
#else
#define FEXP(x) __expf(x)
#define QSCALE 0.125f
#endif

static __device__ __forceinline__ short f2bf(float f) {
  union { float fv; uint32_t u; } v; v.fv = f;
  uint32_t r = v.u + 0x7FFFu + ((v.u >> 16) & 1u);  // RNE
  return (short)(r >> 16);
}

// pack two fp32 -> two bf16 (truncation) in one v_perm_b32
static __device__ __forceinline__ uint32_t pack_trunc(float a, float b) {
  union { float f; uint32_t u; } ua, ub;
  ua.f = a; ub.f = b;
#if __has_builtin(__builtin_amdgcn_perm)
  return __builtin_amdgcn_perm(ub.u, ua.u, 0x07060302u);
#else
  return (ub.u & 0xFFFF0000u) | (ua.u >> 16);
#endif
}

typedef __attribute__((address_space(1))) void as1_void;
typedef __attribute__((address_space(3))) void as3_void;
static __device__ __forceinline__ void gld_lds16(const void* g, void* l) {
  __builtin_amdgcn_global_load_lds((as1_void*)g, (as3_void*)l, 16, 0, 0);
}

// ---------------------------------------------------------------------------
// Kernel 1: fp32 -> bf16 conversion for x, Wq, Wk, Wv, Wo
// ---------------------------------------------------------------------------
__global__ __launch_bounds__(256) void cvt_kernel(
    const float* x, const float* wq, const float* wk, const float* wv,
    const float* wo,
    short* xb, short* wqb, short* wkb, short* wvb, short* wob) {
  int64_t g = (int64_t)blockIdx.x * 256 + threadIdx.x;  // unit = 4 floats
  const int64_t NX = 8388608 / 4, NW = 1048576 / 4;
  const float* src;
  short* dst;
  int64_t i;
  if (g < NX)               { src = x;  dst = xb;  i = g; }
  else if (g < NX + NW)     { src = wq; dst = wqb; i = g - NX; }
  else if (g < NX + 2 * NW) { src = wk; dst = wkb; i = g - NX - NW; }
  else if (g < NX + 3 * NW) { src = wv; dst = wvb; i = g - NX - 2 * NW; }
  else                      { src = wo; dst = wob; i = g - NX - 3 * NW; }
  float4 v = ((const float4*)src)[i];
  short4v o;
  o[0] = f2bf(v.x); o[1] = f2bf(v.y); o[2] = f2bf(v.z); o[3] = f2bf(v.w);
  *(short4v*)&dst[i * 4] = o;
}

// ---------------------------------------------------------------------------
// Kernel 2: fused QKV projection (M=8192, N=1024 x3, K=1024), BK=32.
//   One A-tile stage feeds 3 B-tiles: 48 MFMA per barrier. Double-buffered
//   staging issued right after the barrier.
//   Q: scaled by QSCALE; K,V: masked rows zeroed.
//   Q,K written [bh][t][64] bf16; V written [bh][64][t] bf16 (transposed).
// ---------------------------------------------------------------------------
__global__ __launch_bounds__(256, 2) void qkv3_gemm(
    const short* __restrict__ Xb,
    const short* __restrict__ Wq, const short* __restrict__ Wk,
    const short* __restrict__ Wv,
    const float* __restrict__ bq, const float* __restrict__ bk,
    const float* __restrict__ bv,
    const float* __restrict__ rope, const int* __restrict__ mask,
    short* __restrict__ Qh, short* __restrict__ Kh, short* __restrict__ Vt) {
  __shared__ __align__(16) short As[2][128 * 32];     // 16 KB
  __shared__ __align__(16) short Bs[2][3][128 * 32];  // 48 KB

  const int t = threadIdx.x;
  const int lane = t & 63;
  const int wave = t >> 6;
  const int c = lane & 15;
  const int quad = lane >> 4;
  const int m0 = blockIdx.x * 128;
  const int n0 = blockIdx.y * 128;

  f32x4 zero4 = {0.f, 0.f, 0.f, 0.f};
  f32x4 acc[3][4][4];
#pragma unroll
  for (int m = 0; m < 3; ++m)
#pragma unroll
    for (int i = 0; i < 4; ++i)
#pragma unroll
      for (int j = 0; j < 4; ++j) acc[m][i][j] = zero4;

  const int wm = wave & 1, wn = wave >> 1;

  const int srow = t >> 2;
  const int gc = ((t & 3) - (srow >> 2)) & 3;
  const short* gA = Xb + (size_t)(m0 + srow) * 1024 + gc * 8;
  const short* gW0 = Wq + (size_t)(n0 + srow) * 1024 + gc * 8;
  const short* gW1 = Wk + (size_t)(n0 + srow) * 1024 + gc * 8;
  const short* gW2 = Wv + (size_t)(n0 + srow) * 1024 + gc * 8;

#define QKV_STAGE(buf, k0)                                  \
  do {                                                      \
    gld_lds16(gA + (k0), &As[buf][t * 8]);                  \
    gld_lds16(gA + (k0) + 65536, &As[buf][t * 8 + 2048]);   \
    gld_lds16(gW0 + (k0), &Bs[buf][0][t * 8]);              \
    gld_lds16(gW0 + (k0) + 65536, &Bs[buf][0][t * 8 + 2048]); \
    gld_lds16(gW1 + (k0), &Bs[buf][1][t * 8]);              \
    gld_lds16(gW1 + (k0) + 65536, &Bs[buf][1][t * 8 + 2048]); \
    gld_lds16(gW2 + (k0), &Bs[buf][2][t * 8]);              \
    gld_lds16(gW2 + (k0) + 65536, &Bs[buf][2][t * 8 + 2048]); \
  } while (0)

  QKV_STAGE(0, 0);

  for (int ki = 0; ki < 32; ++ki) {
    __syncthreads();  // drains buf[ki&1] loads (issued one compute phase ago)
    if (ki < 31) QKV_STAGE((ki + 1) & 1, (ki + 1) * 32);

    const short* as = &As[ki & 1][0];
    bf16x8 af[4];
#pragma unroll
    for (int i = 0; i < 4; ++i) {
      int mr = wm * 64 + i * 16 + c;
      af[i] = *(const bf16x8*)&as[mr * 32 + (((quad + (mr >> 2)) & 3) * 8)];
    }
#pragma unroll
    for (int m = 0; m < 3; ++m) {
      const short* bs = &Bs[ki & 1][m][0];
      bf16x8 bfr[4];
#pragma unroll
      for (int j = 0; j < 4; ++j) {
        int nr = wn * 64 + j * 16 + c;
        bfr[j] = *(const bf16x8*)&bs[nr * 32 + (((quad + (nr >> 2)) & 3) * 8)];
      }
#pragma unroll
      for (int i = 0; i < 4; ++i)
#pragma unroll
        for (int j = 0; j < 4; ++j)
          acc[m][i][j] = MFMA16(af[i], bfr[j], acc[m][i][j]);
    }
  }
#undef QKV_STAGE

  // ---- epilogue: C/D layout col=lane&15, row=quad*4+reg ----
  const int nb = n0 + wn * 64;  // wave's 64 cols == one head
  const int hcol = nb >> 6;
  const int bidx = m0 >> 11;
  const int tbase = (m0 & 2047) + wm * 64 + quad * 4;
  const int* mrow = mask + bidx * 2048;

  // Q (mat 0) and K (mat 1): [bh][t][64] with RoPE
#pragma unroll
  for (int mat = 0; mat < 2; ++mat) {
    short* Og = (mat == 0) ? Qh : Kh;
    const float* bias = (mat == 0) ? bq : bk;
    float bj[4];
#pragma unroll
    for (int j = 0; j < 4; ++j) bj[j] = bias[nb + j * 16 + c];
    size_t hb = (size_t)(bidx * 16 + hcol) * 2048;
#pragma unroll
    for (int i = 0; i < 4; ++i) {
#pragma unroll
      for (int r = 0; r < 4; ++r) {
        int tp = tbase + i * 16 + r;
        float f = (mat == 0) ? QSCALE : (mrow[tp] ? 1.0f : 0.0f);
        float cosv = rope[tp * 32 + c];
        float sinv = rope[65536 + tp * 32 + c];
        float v0 = acc[mat][i][0][r] + bj[0];
        float v1 = acc[mat][i][1][r] + bj[1];
        float v2 = acc[mat][i][2][r] + bj[2];
        float v3 = acc[mat][i][3][r] + bj[3];
        size_t base = (hb + tp) * 64;
        Og[base + c]      = f2bf((v0 * cosv - v1 * sinv) * f);
        Og[base + 16 + c] = f2bf((v1 * cosv + v0 * sinv) * f);
        Og[base + 32 + c] = f2bf(v2 * f);
        Og[base + 48 + c] = f2bf(v3 * f);
      }
    }
  }
  // V (mat 2): transposed [bh][d][t], masked t zeroed
  {
    float bj[4];
#pragma unroll
    for (int j = 0; j < 4; ++j) bj[j] = bv[nb + j * 16 + c];
    size_t hb = (size_t)(bidx * 16 + hcol) * 64;
#pragma unroll
    for (int i = 0; i < 4; ++i) {
      int tp = tbase + i * 16;  // multiple of 4
      int4 mv = *(const int4*)&mrow[tp];
      float fr[4];
      fr[0] = mv.x ? 1.f : 0.f; fr[1] = mv.y ? 1.f : 0.f;
      fr[2] = mv.z ? 1.f : 0.f; fr[3] = mv.w ? 1.f : 0.f;
#pragma unroll
      for (int j = 0; j < 4; ++j) {
        short4v pv;
#pragma unroll
        for (int r = 0; r < 4; ++r)
          pv[r] = f2bf((acc[2][i][j][r] + bj[j]) * fr[r]);
        size_t base = (hb + j * 16 + c) * 2048 + tp;
        *(short4v*)&Vt[base] = pv;
      }
    }
  }
}

// ---------------------------------------------------------------------------
// Kernel 3: attention, static softmax, IN-REGISTER P (round-5 rewrite).
//   LDS-bandwidth analysis: previous versions moved ~416 KB/chunk/CU through
//   LDS (frag reads 256 + P round-trip 128 + staging 32) -> LDS-BW-bound at
//   ~37% MfmaUtil regardless of occupancy. This version removes the P
//   round-trip entirely: MFMA contraction over k is a sum, so we pick the
//   k-slot assignment k_phys(ks,quad,j) = (2ks+(j>>2))*16 + quad*4 + (j&3).
//   Under that assignment the PV B-fragment at lane (c,quad) is exactly the
//   exp2'd St[jt][r] values the lane already holds from S^T = K*Q^T
//   (St[jt][r] = S[q=c][jt*16+quad*4+r]) — pure in-register exp+pack.
//   The V A-fragment absorbs the permutation: per (ks,dt), two 8-byte groups
//   at swizzled 8B-units u and u^4 (u = (8ks+quad) ^ 2*(c&7)) instead of one
//   contiguous 16B block. Same bytes, no extra LDS traffic.
//   4 waves x 64 q-rows (256 threads) = lowest LDS-bytes/q-row config.
//   LDS now: K 16 KB + V 16 KB dbuf = 32 KB; traffic 160 KB/chunk/CU (2.6x cut).
//   bh-major grid keeps each head's K/V on one XCD.
// ---------------------------------------------------------------------------
__global__ __launch_bounds__(256, 2) void attn_kernel(
    const short* __restrict__ Qh, const short* __restrict__ Kh,
    const short* __restrict__ Vt, const int* __restrict__ mask,
    short* __restrict__ Og) {
  __shared__ __align__(16) short Ks[2][64 * 64];  // 16 KB
  __shared__ __align__(16) short Vs[2][64 * 64];  // 16 KB

  const int t = threadIdx.x;
  const int lane = t & 63;
  const int wave = t >> 6;  // 0..3
  const int c = lane & 15;
  const int quad = lane >> 4;
  const int bh = blockIdx.x;   // 0..63 (x-major: head -> fixed XCD)
  const int qt = blockIdx.y;   // 0..7 (256 q rows each)
  const int bidx = bh >> 4;
  const short* Qg = Qh + ((size_t)bh * 2048 + qt * 256) * 64;
  const short* Kg = Kh + (size_t)bh * 2048 * 64;
  const short* Vg = Vt + (size_t)bh * 64 * 2048;

  // count masked keys for this batch; full butterfly so every lane holds the
  // total (in-register, no LDS scalar / extra barrier dependence)
  float nm;
  {
    const int4* mr = (const int4*)(mask + bidx * 2048);
    int cnt = 0;
#pragma unroll
    for (int k = 0; k < 8; ++k) {
      int4 a = mr[k * 64 + lane];
      cnt += (a.x == 0) + (a.y == 0) + (a.z == 0) + (a.w == 0);
    }
    cnt += __shfl_xor(cnt, 1);  cnt += __shfl_xor(cnt, 2);
    cnt += __shfl_xor(cnt, 4);  cnt += __shfl_xor(cnt, 8);
    cnt += __shfl_xor(cnt, 16); cnt += __shfl_xor(cnt, 32);
    nm = (float)cnt;
  }

  // Q fragments (B-operand), loop-invariant; wave covers 64 q rows (it 0..3)
  bf16x8 qf[2][4];
#pragma unroll
  for (int ks = 0; ks < 2; ++ks)
#pragma unroll
    for (int it = 0; it < 4; ++it)
      qf[ks][it] =
          *(const bf16x8*)&Qg[(wave * 64 + it * 16 + c) * 64 + ks * 32 + quad * 8];

  const bf16x8 ones = {0x3F80, 0x3F80, 0x3F80, 0x3F80,
                       0x3F80, 0x3F80, 0x3F80, 0x3F80};  // bf16 1.0 x8

  f32x4 zero4 = {0.f, 0.f, 0.f, 0.f};
  f32x4 O[4][4];
#pragma unroll
  for (int dt = 0; dt < 4; ++dt)
#pragma unroll
    for (int it = 0; it < 4; ++it) O[dt][it] = zero4;
  f32x4 Ol[4] = {zero4, zero4, zero4, zero4};

  // staging: 256 threads x 4 x 16B = 64x64 K tile + 64x64 V tile per chunk
  const int krow0 = t >> 3;                 // 0..31
  const int klc = (t & 7) ^ (krow0 & 7);    // XOR-swizzled 16B col block
  const short* gk0 = Kg + (size_t)krow0 * 64 + klc * 8;
  const short* gv0 = Vg + (size_t)krow0 * 2048 + klc * 8;

  // prologue: stage chunk 0 into buffer 0
  gld_lds16(gk0, &Ks[0][t * 8]);
  gld_lds16(gk0 + 32 * 64, &Ks[0][t * 8 + 2048]);
  gld_lds16(gv0, &Vs[0][t * 8]);
  gld_lds16(gv0 + 32 * 2048, &Vs[0][t * 8 + 2048]);

  const int s2 = (c & 7) * 2;  // 8B-unit swizzle for V fragment reads

  for (int ci = 0; ci < 32; ++ci) {
    __syncthreads();  // drains chunk-ci loads (issued one compute-phase ago)
    if (ci < 31) {
      int cn = (ci + 1) * 64;
      int nb = (ci + 1) & 1;
      gld_lds16(gk0 + (size_t)cn * 64, &Ks[nb][t * 8]);
      gld_lds16(gk0 + (size_t)(cn + 32) * 64, &Ks[nb][t * 8 + 2048]);
      gld_lds16(gv0 + cn, &Vs[nb][t * 8]);
      gld_lds16(gv0 + cn + 32 * 2048, &Vs[nb][t * 8 + 2048]);
    }
    const short* ksb = &Ks[ci & 1][0];
    const short* vsb = &Vs[ci & 1][0];

    // hoisted K fragments (A-operand of S^T), contiguous 16B swizzled blocks
    bf16x8 ak[2][4];
#pragma unroll
    for (int ks = 0; ks < 2; ++ks)
#pragma unroll
      for (int jt = 0; jt < 4; ++jt)
        ak[ks][jt] = *(const bf16x8*)&ksb[(jt * 16 + c) * 64 +
                                          (((4 * ks + quad) ^ (c & 7)) * 8)];

    // hoisted V fragments (A-operand of PV) under the k-slot permutation:
    // slot j of av[ks][dt] = V^T[dt*16+c][(2ks+(j>>2))*16 + quad*4 + (j&3)]
    // -> two 8B groups at swizzled units u and u^4.
    bf16x8 av[2][4];
#pragma unroll
    for (int ks = 0; ks < 2; ++ks)
#pragma unroll
      for (int dt = 0; dt < 4; ++dt) {
        int u = (8 * ks + quad) ^ s2;
        int rowb = (dt * 16 + c) * 64;
        short4v lo = *(const short4v*)&vsb[rowb + u * 4];
        short4v hi = *(const short4v*)&vsb[rowb + (u ^ 4) * 4];
        union { short4v h[2]; bf16x8 v; } uu;
        uu.h[0] = lo; uu.h[1] = hi;
        av[ks][dt] = uu.v;
      }

#pragma unroll
    for (int it = 0; it < 4; ++it) {  // four 16-row q sub-blocks
      f32x4 St[4];
#pragma unroll
      for (int jt = 0; jt < 4; ++jt)
        St[jt] = MFMA16(ak[0][jt], qf[0][it], zero4);
#pragma unroll
      for (int jt = 0; jt < 4; ++jt)
        St[jt] = MFMA16(ak[1][jt], qf[1][it], St[jt]);

      // exp2 + pack -> PV B-fragments, entirely in-register.
      bf16x8 bp[2];
#pragma unroll
      for (int ks = 0; ks < 2; ++ks) {
        union { uint32_t w[4]; bf16x8 v; } uu;
        uu.w[0] = pack_trunc(FEXP(St[2 * ks][0]),     FEXP(St[2 * ks][1]));
        uu.w[1] = pack_trunc(FEXP(St[2 * ks][2]),     FEXP(St[2 * ks][3]));
        uu.w[2] = pack_trunc(FEXP(St[2 * ks + 1][0]), FEXP(St[2 * ks + 1][1]));
        uu.w[3] = pack_trunc(FEXP(St[2 * ks + 1][2]), FEXP(St[2 * ks + 1][3]));
        bp[ks] = uu.v;
      }

#pragma unroll
      for (int ks = 0; ks < 2; ++ks) {
        Ol[it] = MFMA16(ones, bp[ks], Ol[it]);
#pragma unroll
        for (int dt = 0; dt < 4; ++dt)
          O[dt][it] = MFMA16(av[ks][dt], bp[ks], O[dt][it]);
      }
    }
  }

#pragma unroll
  for (int it = 0; it < 4; ++it) {
    float inv = 1.0f / (Ol[it][0] - nm);  // remove masked keys' exp2(0)=1
    int tq = qt * 256 + wave * 64 + it * 16 + c;
    size_t rb = ((size_t)bidx * 2048 + tq) * 1024 + (size_t)(bh & 15) * 64;
#pragma unroll
    for (int dt = 0; dt < 4; ++dt) {
      short4v ov;
#pragma unroll
      for (int r = 0; r < 4; ++r) ov[r] = f2bf(O[dt][it][r] * inv);
      *(short4v*)&Og[rb + dt * 16 + quad * 4] = ov;
    }
  }
}

// ---------------------------------------------------------------------------
// Kernel 4: output projection GEMM: out = attout @ Wo^T + bo (fp32 out).
//   64x128 tile, BK=32, double-buffered staging -> 1024 blocks, 24 KB LDS.
// ---------------------------------------------------------------------------
__global__ __launch_bounds__(256) void out_gemm(
    const short* __restrict__ Ab, const short* __restrict__ Wob,
    const float* __restrict__ bo, float* __restrict__ out) {
  __shared__ __align__(16) short As[2][64 * 32];   // 8 KB
  __shared__ __align__(16) short Bs[2][128 * 32];  // 16 KB

  const int t = threadIdx.x;
  const int lane = t & 63;
  const int wave = t >> 6;
  const int c = lane & 15;
  const int quad = lane >> 4;
  const int m0 = blockIdx.x * 64;
  const int n0 = blockIdx.y * 128;

  f32x4 zero4 = {0.f, 0.f, 0.f, 0.f};
  f32x4 acc[4][2];
#pragma unroll
  for (int i = 0; i < 4; ++i) {
    acc[i][0] = zero4;
    acc[i][1] = zero4;
  }

  const int srow = t >> 2;
  const int gc = ((t & 3) - (srow >> 2)) & 3;
  const short* gA = Ab + (size_t)(m0 + srow) * 1024 + gc * 8;
  const short* gB = Wob + (size_t)(n0 + srow) * 1024 + gc * 8;

#define OUT_STAGE(buf, k0)                                   \
  do {                                                       \
    gld_lds16(gA + (k0), &As[buf][t * 8]);                   \
    gld_lds16(gB + (k0), &Bs[buf][t * 8]);                   \
    gld_lds16(gB + (k0) + 65536, &Bs[buf][t * 8 + 2048]);    \
  } while (0)

  OUT_STAGE(0, 0);

  for (int ki = 0; ki < 32; ++ki) {
    __syncthreads();
    if (ki < 31) OUT_STAGE((ki + 1) & 1, (ki + 1) * 32);

    const short* as = &As[ki & 1][0];
    const short* bs = &Bs[ki & 1][0];
    bf16x8 af[4], bfr[2];
#pragma unroll
    for (int i = 0; i < 4; ++i) {
      int mr = i * 16 + c;
      af[i] = *(const bf16x8*)&as[mr * 32 + (((quad + (mr >> 2)) & 3) * 8)];
    }
#pragma unroll
    for (int j = 0; j < 2; ++j) {
      int nr = wave * 32 + j * 16 + c;
      bfr[j] = *(const bf16x8*)&bs[nr * 32 + (((quad + (nr >> 2)) & 3) * 8)];
    }
#pragma unroll
    for (int i = 0; i < 4; ++i) {
      acc[i][0] = MFMA16(af[i], bfr[0], acc[i][0]);
      acc[i][1] = MFMA16(af[i], bfr[1], acc[i][1]);
    }
  }
#undef OUT_STAGE

  const int nb = n0 + wave * 32;
  float bj[2];
  bj[0] = bo[nb + c];
  bj[1] = bo[nb + 16 + c];
#pragma unroll
  for (int i = 0; i < 4; ++i) {
    int m = m0 + i * 16 + quad * 4;
#pragma unroll
    for (int r = 0; r < 4; ++r) {
      float* orow = out + (size_t)(m + r) * 1024 + nb;
      orow[c]      = acc[i][0][r] + bj[0];
      orow[16 + c] = acc[i][1][r] + bj[1];
    }
  }
}

// ---------------------------------------------------------------------------
extern "C" void kernel_launch(void* const* d_in, const int* in_sizes, int n_in,
                              void* d_out, int out_size, void* d_ws,
                              size_t ws_size, hipStream_t stream) {
  const float* x    = (const float*)d_in[0];
  const float* rope = (const float*)d_in[1];
  const int*   mask = (const int*)d_in[2];
  const float* Wq   = (const float*)d_in[3];
  const float* bq   = (const float*)d_in[4];
  const float* Wk   = (const float*)d_in[5];
  const float* bk   = (const float*)d_in[6];
  const float* Wv   = (const float*)d_in[7];
  const float* bv   = (const float*)d_in[8];
  const float* Wo   = (const float*)d_in[9];
  const float* bo   = (const float*)d_in[10];
  float* out = (float*)d_out;

  char* ws = (char*)d_ws;
  short* xb  = (short*)(ws);               // 16 MB; reused as attout later
  short* wqb = (short*)(ws + 16777216);    // 2 MB each
  short* wkb = (short*)(ws + 18874368);
  short* wvb = (short*)(ws + 20971520);
  short* wob = (short*)(ws + 23068672);
  short* Qh  = (short*)(ws + 25198592);    // 16 MB  [bh][t][64]
  short* Kh  = (short*)(ws + 41975808);    // 16 MB  [bh][t][64]
  short* Vt  = (short*)(ws + 58753024);    // 16 MB  [bh][64][t]
  short* att = xb;  // safe: xb consumed by qkv3_gemm before attn writes

  cvt_kernel<<<12288, 256, 0, stream>>>(x, Wq, Wk, Wv, Wo, xb, wqb, wkb, wvb,
                                        wob);
  qkv3_gemm<<<dim3(64, 8), 256, 0, stream>>>(xb, wqb, wkb, wvb, bq, bk, bv,
                                             rope, mask, Qh, Kh, Vt);
  attn_kernel<<<dim3(64, 8), 256, 0, stream>>>(Qh, Kh, Vt, mask, att);
  out_gemm<<<dim3(128, 8), 256, 0, stream>>>(att, wob, bo, out);
}